// Round 6
// baseline (941.690 us; speedup 1.0000x reference)
//
#include <hip/hip_runtime.h>

#define IN_DIM   512
#define OUT_DIM  256
#define N_MID    1280
#define N_NODES  1792
#define BATCH    16384
#define NT       256
#define XPAD     520      // fallback kernel x stride

// net4 geometry: 256 blocks x 1024 threads, 64 rows/block, 16 waves.
// TPW col-tiles (16 cols each) per wave, all 4 row-groups per wave.
// Mpad = TPW*256: TPW=3 -> 768, TPW=4 -> 1024. Mc>1024 -> net_v1 fallback.
// R4/R5 lesson: register spills (596 MB HBM scratch traffic) were 100% of the
// wall. Fix: amdgpu_waves_per_eu(4,4) (128-reg budget) + resolver split into
// 16-reg halves + unroll 1 on phase-1 k-loop to cap scheduler pressure.

// ---- workspace layout (max geometry: tpm=64, ksteps=48, nch=32) ----
#define EW2_ELEMS ((size_t)48 * 64 * 64 * 8)               // bf16 elems = 1,572,864
#define EW2_BYTES (EW2_ELEMS * 2)                          // 3,145,728
#define TRI_OFF   EW2_BYTES
#define TRI_BYTES ((size_t)32 * 1024 * 4)                  // 131,072
#define HDR_OFF   (TRI_OFF + TRI_BYTES)
#define CMAP_OFF  (HDR_OFF + 32)
#define OCOL_OFF  (CMAP_OFF + N_MID * 4)
#define BIASC_OFF (OCOL_OFF + N_MID * 4)
#define WS_NEED   (BIASC_OFF + N_MID * 4)

typedef __attribute__((ext_vector_type(8))) short  bfrag;
typedef __attribute__((ext_vector_type(4))) float  ffrag;

__device__ __forceinline__ unsigned short f2bf(float f) {
    unsigned int u = __float_as_uint(f);
    u += 0x7FFFu + ((u >> 16) & 1u);       // RNE
    return (unsigned short)(u >> 16);
}
__device__ __forceinline__ float bf2f(unsigned short v) {
    return __uint_as_float(((unsigned int)v) << 16);
}

// ============================================================
// Setup A: compact existing columns (1 wave).
// hdr = {Mc, Mpad, unused, nch=Mpad/32, tpm=Mpad/16}
// ============================================================
__global__ void build_maps_kernel(const int* __restrict__ exist,
                                  const float* __restrict__ bias,
                                  int* __restrict__ hdr,
                                  int* __restrict__ cmap,
                                  int* __restrict__ ocol,
                                  float* __restrict__ biasc) {
    const int lane = threadIdx.x;   // 64
    int base = 0;
    for (int r = 0; r < N_MID / 64; ++r) {
        const int i = r * 64 + lane;
        const int e = exist[i];
        const unsigned long long m  = __ballot(e != 0);
        const unsigned long long lt = (lane == 0) ? 0ull : (~0ull >> (64 - lane));
        const int pos = base + __popcll(m & lt);
        if (e) {
            cmap[pos]  = i;
            ocol[pos]  = (i >= N_MID - OUT_DIM) ? (i - (N_MID - OUT_DIM)) : -1;
            biasc[pos] = bias[i];
        }
        base += __popcll(m);
    }
    for (int idx = base + lane; idx < N_MID; idx += 64) {
        cmap[idx] = 0; ocol[idx] = -1; biasc[idx] = 0.f;
    }
    if (lane == 0) {
        const int Mc = base;
        int Mpad;
        if (Mc <= 768) Mpad = 768;
        else if (Mc <= 1024) Mpad = 1024;
        else Mpad = (Mc + 127) & ~127;     // v1 fallback territory
        hdr[0] = Mc; hdr[1] = Mpad; hdr[2] = 0;
        hdr[3] = Mpad / 32; hdr[4] = Mpad / 16;
    }
}

// ============================================================
// Setup B: gather eff_w -> bf16 MFMA B-fragment-major.
// ============================================================
__global__ __launch_bounds__(NT)
void gather2_kernel(const float* __restrict__ w, const int* __restrict__ conn,
                    const int* __restrict__ hdr, const int* __restrict__ cmap,
                    unsigned short* __restrict__ ew2) {
    const int Mc = hdr[0], nch = hdr[3], tpm = hdr[4];
    if (tpm > 64) return;                      // v1 fallback case
    const int tid  = blockIdx.x * NT + threadIdx.x;
    const int lane = tid & 63;
    const int gl   = tid >> 6;
    const int gt   = gl % tpm;
    const int kstep = gl / tpm;
    if (kstep >= 16 + nch) return;
    const int c  = gt * 16 + (lane & 15);
    const int k0 = kstep * 32 + ((lane >> 4) << 3);
    unsigned short v[8];
#pragma unroll
    for (int jj = 0; jj < 8; ++jj) {
        const int s = k0 + jj;
        float val = 0.f;
        if (c < Mc) {
            const int cc = cmap[c];
            if (s < IN_DIM) {
                const size_t o = (size_t)s * N_MID + cc;
                val = w[o] * (float)conn[o];
            } else {
                const int s2 = s - IN_DIM;
                if (s2 < Mc && s2 < c && (s2 >> 5) != (c >> 5)) {
                    const size_t o = (size_t)(IN_DIM + cmap[s2]) * N_MID + cc;
                    val = w[o] * (float)conn[o];
                }
            }
        }
        v[jj] = f2bf(val);
    }
    *(uint4*)&ew2[((size_t)(kstep * tpm + gt) * 64 + lane) * 8] = *(uint4*)v;
}

// ============================================================
// Setup C: in-chunk triangle, fp32. tri[j][sl][cl] nonzero iff sl<cl && col<Mc.
// ============================================================
__global__ __launch_bounds__(NT)
void gather_tri_kernel(const float* __restrict__ w, const int* __restrict__ conn,
                       const int* __restrict__ hdr, const int* __restrict__ cmap,
                       float* __restrict__ tri) {
    const int Mc = hdr[0], nch = hdr[3];
    const int idx = blockIdx.x * NT + threadIdx.x;   // < 32*1024
    const int j  = idx >> 10;
    if (j >= nch) return;
    const int sl = (idx >> 5) & 31;
    const int cl = idx & 31;
    const int s = j * 32 + sl, c = j * 32 + cl;
    float v = 0.f;
    if (sl < cl && c < Mc) {
        const size_t o = (size_t)(IN_DIM + cmap[s]) * N_MID + cmap[c];
        v = w[o] * (float)conn[o];
    }
    tri[idx] = v;
}

// ============================================================
// Main kernel (net4): 1 block/CU, 16 waves, 64 rows.
// ============================================================
template <int TPW>
__global__ __launch_bounds__(1024)
__attribute__((amdgpu_waves_per_eu(4, 4)))
void net4_kernel(const float* __restrict__ x,
                 const unsigned short* __restrict__ ew2,
                 const float* __restrict__ tri_g,
                 const int* __restrict__ hdr,
                 const int* __restrict__ ocol,
                 const float* __restrict__ biasc,
                 float* __restrict__ out) {
    if (hdr[1] != TPW * 256) return;
    const int Mc  = hdr[0];
    const int tpm = hdr[4];                    // TPW*16
    const int nch = TPW * 8;

    __shared__ __align__(16) unsigned short xa[64 * 520];        // 66,560 B
    __shared__ float stage[64 * 33];                             //  8,448 B
    __shared__ __align__(16) unsigned short res_lds[2][64 * 40]; // 10,240 B
    __shared__ __align__(16) float tri_lds[2][1024];             //  8,192 B
    __shared__ float bias_lds[1024];                             //  4,096 B
    __shared__ int   ocol_lds[1024];                             //  4,096 B

    const int t = threadIdx.x, lane = t & 63, w = t >> 6;
    const int l15 = lane & 15, q = lane >> 4;
    const int r0 = blockIdx.x * 64;
    const int g0 = w * TPW;

    // ---- stage bias/ocol + tri chunk 0 + x->bf16 A-layout ----
    for (int i = t; i < TPW * 256; i += 1024) {
        bias_lds[i] = biasc[i];
        ocol_lds[i] = ocol[i];
    }
    if (w == 15) {
        const float4* src = (const float4*)tri_g;
#pragma unroll
        for (int u = 0; u < 4; ++u) {
            const float4 v = src[lane + 64 * u];
            *(float4*)&tri_lds[0][(lane + 64 * u) * 4] = v;
        }
    }
    {
        const float4* xg = (const float4*)(x + (size_t)r0 * IN_DIM);
        for (int i = t; i < 64 * 128; i += 1024) {
            const int row = i >> 7, k4 = i & 127;
            const float4 f = xg[i];
            unsigned short vv[4] = {f2bf(f.x), f2bf(f.y), f2bf(f.z), f2bf(f.w)};
            *(uint2*)&xa[row * 520 + k4 * 4] = *(uint2*)vv;
        }
    }
    __syncthreads();

    ffrag acc[TPW][4];
#pragma unroll
    for (int tt = 0; tt < TPW; ++tt)
#pragma unroll
        for (int rr = 0; rr < 4; ++rr) acc[tt][rr] = (ffrag)0.f;

    // ---- phase 1: input GEMM, 16 k-steps (unroll 1: cap reg pressure) ----
#pragma unroll 1
    for (int kb = 0; kb < 16; ++kb) {
        bfrag a[4];
#pragma unroll
        for (int rr = 0; rr < 4; ++rr)
            a[rr] = *(const bfrag*)&xa[(rr * 16 + l15) * 520 + kb * 32 + q * 8];
#pragma unroll
        for (int tt = 0; tt < TPW; ++tt) {
            if ((g0 + tt) * 16 < Mc) {
                const bfrag b = *(const bfrag*)&ew2[((size_t)(kb * tpm + g0 + tt) * 64 + lane) * 8];
#pragma unroll
                for (int rr = 0; rr < 4; ++rr)
                    acc[tt][rr] = __builtin_amdgcn_mfma_f32_16x16x32_bf16(a[rr], b, acc[tt][rr], 0, 0, 0);
            }
        }
    }

    // ---- phase 2: sequential chunks ----
#pragma unroll 1
    for (int j = 0; j < nch; ++j) {
        const int cbase = 32 * j;
        if (cbase >= Mc) break;                      // uniform

        if (j > 0) {                                 // apply res_{j-1}
            const int pr = (j - 1) & 1;
            bfrag a[4];
#pragma unroll
            for (int rr = 0; rr < 4; ++rr)
                a[rr] = *(const bfrag*)&res_lds[pr][(rr * 16 + l15) * 40 + q * 8];
#pragma unroll
            for (int tt = 0; tt < TPW; ++tt) {
                const int col0 = (g0 + tt) * 16;
                if (col0 >= cbase && col0 < Mc) {
                    const bfrag b = *(const bfrag*)&ew2[((size_t)((15 + j) * tpm + g0 + tt) * 64 + lane) * 8];
#pragma unroll
                    for (int rr = 0; rr < 4; ++rr)
                        acc[tt][rr] = __builtin_amdgcn_mfma_f32_16x16x32_bf16(a[rr], b, acc[tt][rr], 0, 0, 0);
                }
            }
        }

        // stage chunk tiles (C-layout -> [row][col])
#pragma unroll
        for (int tt = 0; tt < TPW; ++tt) {
            const int g = g0 + tt;
            if (g == 2 * j || g == 2 * j + 1) {
                const int half = (g & 1) ? 16 : 0;
#pragma unroll
                for (int rr = 0; rr < 4; ++rr)
#pragma unroll
                    for (int r = 0; r < 4; ++r)
                        stage[(rr * 16 + 4 * q + r) * 33 + half + l15] = acc[tt][rr][r];
            }
        }
        __syncthreads();                             // A

        const int rsv = j & 15;
        if (w == rsv) {
            // transposed resolve, two 16-reg halves: lane = batch row
            const float* trij = tri_lds[j & 1];
            unsigned short* resw = &res_lds[j & 1][lane * 40];
            {   // half 0: cols 0..15
                float reg[16];
#pragma unroll
                for (int c = 0; c < 16; ++c) reg[c] = stage[lane * 33 + c];
#pragma unroll
                for (int c = 0; c < 16; ++c) {
                    const float s  = __fdividef(1.f, 1.f + __expf(-reg[c]));
                    const float rs = s + bias_lds[cbase + c];
                    resw[c] = f2bf(rs);
                    const int oc = ocol_lds[cbase + c];
                    if (oc >= 0)
                        out[(size_t)(r0 + lane) * OUT_DIM + oc] = rs;
#pragma unroll
                    for (int k = c + 1; k < 16; ++k)
                        reg[k] = fmaf(rs, trij[c * 32 + k], reg[k]);
                }
            }
            {   // half 1: cols 16..31 (cross-half via bf16 res from LDS)
                float reg[16];
#pragma unroll
                for (int k = 0; k < 16; ++k) reg[k] = stage[lane * 33 + 16 + k];
#pragma unroll
                for (int c = 0; c < 16; ++c) {
                    const float rsb = bf2f(resw[c]);
#pragma unroll
                    for (int k = 0; k < 16; ++k)
                        reg[k] = fmaf(rsb, trij[c * 32 + 16 + k], reg[k]);
                }
#pragma unroll
                for (int c = 0; c < 16; ++c) {
                    const float s  = __fdividef(1.f, 1.f + __expf(-reg[c]));
                    const float rs = s + bias_lds[cbase + 16 + c];
                    resw[16 + c] = f2bf(rs);
                    const int oc = ocol_lds[cbase + 16 + c];
                    if (oc >= 0)
                        out[(size_t)(r0 + lane) * OUT_DIM + oc] = rs;
#pragma unroll
                    for (int k = c + 1; k < 16; ++k)
                        reg[k] = fmaf(rs, trij[(16 + c) * 32 + 16 + k], reg[k]);
                }
            }
        } else if (w == ((rsv + 8) & 15)) {
            // prefetch tri for chunk j+1 (overlapped with resolve)
            const int jn = j + 1;
            if (jn < nch && 32 * jn < Mc) {
                const float4* src = (const float4*)(tri_g + (size_t)jn * 1024);
#pragma unroll
                for (int u = 0; u < 4; ++u) {
                    const float4 v = src[lane + 64 * u];
                    *(float4*)&tri_lds[jn & 1][(lane + 64 * u) * 4] = v;
                }
            }
        }
        __syncthreads();                             // B
    }
}

// ============================================================
// Fallback (Mc > 1024 or tiny ws): round-1 monolithic fp32 kernel.
// ============================================================
__global__ __launch_bounds__(NT, 4)
void net_v1_kernel(const float* __restrict__ x,
                   const float* __restrict__ wsrc,
                   const int* __restrict__ conn,
                   const float* __restrict__ bias,
                   const int* __restrict__ exist,
                   const int* __restrict__ hdr,   // null = always run
                   float* __restrict__ out) {
    if (hdr && hdr[1] <= 1024) return;
    __shared__ float xs[16 * XPAD];
    __shared__ float res_s[2][16];
    float* bias_s  = xs;
    float* exist_s = xs + N_MID;
    const int t = threadIdx.x, rg = t & 3, cg = t >> 2;
    const int r0 = blockIdx.x * 16;
    const int c0 = cg * 20;
    {
        const float4* xg = (const float4*)(x + (size_t)r0 * IN_DIM);
        for (int idx = t; idx < 16 * IN_DIM / 4; idx += NT) {
            const int r = idx >> 7, jj = idx & 127;
            *(float4*)&xs[r * XPAD + jj * 4] = xg[idx];
        }
    }
    __syncthreads();
    float acc[4][20];
#pragma unroll
    for (int a = 0; a < 4; ++a)
#pragma unroll
        for (int k = 0; k < 20; ++k) acc[a][k] = 0.f;
    for (int j = 0; j < IN_DIM; ++j) {
        const size_t woff = (size_t)j * N_MID + c0;
        const float xv0 = xs[rg * XPAD + j];
        const float xv1 = xs[(rg + 4) * XPAD + j];
        const float xv2 = xs[(rg + 8) * XPAD + j];
        const float xv3 = xs[(rg + 12) * XPAD + j];
#pragma unroll
        for (int qq = 0; qq < 5; ++qq) {
            float4 w4 = *(const float4*)(wsrc + woff + qq * 4);
            const int4 c4 = *(const int4*)(conn + woff + qq * 4);
            w4.x *= (float)c4.x; w4.y *= (float)c4.y;
            w4.z *= (float)c4.z; w4.w *= (float)c4.w;
            const float wq[4] = {w4.x, w4.y, w4.z, w4.w};
#pragma unroll
            for (int u = 0; u < 4; ++u) {
                const int k = qq * 4 + u;
                acc[0][k] = fmaf(xv0, wq[u], acc[0][k]);
                acc[1][k] = fmaf(xv1, wq[u], acc[1][k]);
                acc[2][k] = fmaf(xv2, wq[u], acc[2][k]);
                acc[3][k] = fmaf(xv3, wq[u], acc[3][k]);
            }
        }
    }
    __syncthreads();
    for (int idx = t; idx < N_MID; idx += NT) {
        bias_s[idx]  = bias[idx];
        exist_s[idx] = (float)exist[idx];
    }
    __syncthreads();
    int p = 0;
    for (int bb = 0; bb < 64; ++bb) {
#pragma unroll
        for (int kk = 0; kk < 20; ++kk) {
            const int i = bb * 20 + kk;
            const float e = exist_s[i];
            if (e != 0.f) {
                if (cg == bb) {
                    const float bv = bias_s[i];
#pragma unroll
                    for (int a = 0; a < 4; ++a) {
                        const float v = acc[a][kk];
                        const float s = __fdividef(1.f, 1.f + __expf(-v));
                        const float res = (s + bv) * e;
                        res_s[p][rg + 4 * a] = res;
                        if (i >= N_MID - OUT_DIM)
                            out[(size_t)(r0 + rg + 4 * a) * OUT_DIM + (i - (N_MID - OUT_DIM))] = res;
                    }
                }
                __syncthreads();
                const float rv0 = res_s[p][rg];
                const float rv1 = res_s[p][rg + 4];
                const float rv2 = res_s[p][rg + 8];
                const float rv3 = res_s[p][rg + 12];
                const size_t woff = (size_t)(IN_DIM + i) * N_MID + c0;
                if (cg > bb) {
#pragma unroll
                    for (int qq = 0; qq < 5; ++qq) {
                        float4 w4 = *(const float4*)(wsrc + woff + qq * 4);
                        const int4 c4 = *(const int4*)(conn + woff + qq * 4);
                        w4.x *= (float)c4.x; w4.y *= (float)c4.y;
                        w4.z *= (float)c4.z; w4.w *= (float)c4.w;
                        const float wq[4] = {w4.x, w4.y, w4.z, w4.w};
#pragma unroll
                        for (int u = 0; u < 4; ++u) {
                            const int k = qq * 4 + u;
                            acc[0][k] = fmaf(rv0, wq[u], acc[0][k]);
                            acc[1][k] = fmaf(rv1, wq[u], acc[1][k]);
                            acc[2][k] = fmaf(rv2, wq[u], acc[2][k]);
                            acc[3][k] = fmaf(rv3, wq[u], acc[3][k]);
                        }
                    }
                } else if (cg == bb) {
#pragma unroll
                    for (int k = kk + 1; k < 20; ++k) {
                        float ww = wsrc[woff + k] * (float)conn[woff + k];
                        acc[0][k] = fmaf(rv0, ww, acc[0][k]);
                        acc[1][k] = fmaf(rv1, ww, acc[1][k]);
                        acc[2][k] = fmaf(rv2, ww, acc[2][k]);
                        acc[3][k] = fmaf(rv3, ww, acc[3][k]);
                    }
                }
                p ^= 1;
            }
        }
    }
}

extern "C" void kernel_launch(void* const* d_in, const int* in_sizes, int n_in,
                              void* d_out, int out_size, void* d_ws, size_t ws_size,
                              hipStream_t stream) {
    const float* x      = (const float*)d_in[0];
    const float* weight = (const float*)d_in[1];
    const float* bias   = (const float*)d_in[2];
    const int*   conn   = (const int*)d_in[3];
    const int*   exist  = (const int*)d_in[4];
    float*       out    = (float*)d_out;

    if (ws_size >= WS_NEED) {
        char* ws = (char*)d_ws;
        unsigned short* ew2  = (unsigned short*)ws;
        float*          tri  = (float*)(ws + TRI_OFF);
        int*            hdr  = (int*)(ws + HDR_OFF);
        int*            cmap = (int*)(ws + CMAP_OFF);
        int*            ocolp= (int*)(ws + OCOL_OFF);
        float*          bsc  = (float*)(ws + BIASC_OFF);

        build_maps_kernel<<<1, 64, 0, stream>>>(exist, bias, hdr, cmap, ocolp, bsc);
        gather2_kernel<<<768, NT, 0, stream>>>(weight, conn, hdr, cmap, ew2);
        gather_tri_kernel<<<128, NT, 0, stream>>>(weight, conn, hdr, cmap, tri);
        net4_kernel<3><<<BATCH / 64, 1024, 0, stream>>>(x, ew2, tri, hdr, ocolp, bsc, out);
        net4_kernel<4><<<BATCH / 64, 1024, 0, stream>>>(x, ew2, tri, hdr, ocolp, bsc, out);
        net_v1_kernel<<<BATCH / 16, NT, 0, stream>>>(x, weight, conn, bias, exist, hdr, out);
    } else {
        net_v1_kernel<<<BATCH / 16, NT, 0, stream>>>(x, weight, conn, bias, exist, nullptr, out);
    }
}

// Round 7
// 365.078 us; speedup vs baseline: 2.5794x; 2.5794x over previous
//
#include <hip/hip_runtime.h>

#define IN_DIM   512
#define OUT_DIM  256
#define N_MID    1280
#define BATCH    16384
#define NT       256
#define XPAD     520      // fallback kernel x stride

// net5 geometry: 256 blocks x 512 threads (8 waves), 64 rows/block.
// LDS ~98 KB -> 1 block/CU -> 2 waves/SIMD -> 256-reg/wave budget (m69).
// R4-R6 lesson: at 16 waves/CU the budget is 128 and arch spills (600 MB
// scratch HBM traffic = entire wall). Halving waves doubles the budget.
// Wave w owns TPW=Mpad/128 col-tiles x 4 row-groups; acc[TPW][4] ffrags.

// ---- workspace layout (max geometry: ksteps=48, tpm=64, nch=32) ----
#define EW2_ELEMS ((size_t)48 * 64 * 64 * 8)               // bf16 elems
#define EW2_BYTES (EW2_ELEMS * 2)                          // 3,145,728
#define TRI_OFF   EW2_BYTES
#define TRI_BYTES ((size_t)32 * 1024 * 4)                  // 131,072
#define HDR_OFF   (TRI_OFF + TRI_BYTES)
#define CMAP_OFF  (HDR_OFF + 32)
#define OCOL_OFF  (CMAP_OFF + N_MID * 4)
#define BIASC_OFF (OCOL_OFF + N_MID * 4)
#define WS_NEED   (BIASC_OFF + N_MID * 4)

typedef __attribute__((ext_vector_type(8))) short  bfrag;
typedef __attribute__((ext_vector_type(4))) float  ffrag;

__device__ __forceinline__ unsigned short f2bf(float f) {
    unsigned int u = __float_as_uint(f);
    u += 0x7FFFu + ((u >> 16) & 1u);       // RNE
    return (unsigned short)(u >> 16);
}

// ============================================================
// Setup A: compact existing columns (1 wave).
// hdr = {Mc, Mpad, unused, nch=Mpad/32, tpm=Mpad/16}
// ============================================================
__global__ void build_maps_kernel(const int* __restrict__ exist,
                                  const float* __restrict__ bias,
                                  int* __restrict__ hdr,
                                  int* __restrict__ cmap,
                                  int* __restrict__ ocol,
                                  float* __restrict__ biasc) {
    const int lane = threadIdx.x;   // 64
    int base = 0;
    for (int r = 0; r < N_MID / 64; ++r) {
        const int i = r * 64 + lane;
        const int e = exist[i];
        const unsigned long long m  = __ballot(e != 0);
        const unsigned long long lt = (lane == 0) ? 0ull : (~0ull >> (64 - lane));
        const int pos = base + __popcll(m & lt);
        if (e) {
            cmap[pos]  = i;
            ocol[pos]  = (i >= N_MID - OUT_DIM) ? (i - (N_MID - OUT_DIM)) : -1;
            biasc[pos] = bias[i];
        }
        base += __popcll(m);
    }
    for (int idx = base + lane; idx < N_MID; idx += 64) {
        cmap[idx] = 0; ocol[idx] = -1; biasc[idx] = 0.f;
    }
    if (lane == 0) {
        const int Mc = base;
        int Mpad;
        if (Mc <= 768) Mpad = 768;
        else if (Mc <= 1024) Mpad = 1024;
        else Mpad = (Mc + 127) & ~127;     // v1 fallback territory
        hdr[0] = Mc; hdr[1] = Mpad; hdr[2] = 0;
        hdr[3] = Mpad / 32; hdr[4] = Mpad / 16;
    }
}

// ============================================================
// Setup B: gather eff_w -> bf16 MFMA B-fragment-major.
// ew2[((kstep*tpm + gt)*64 + lane)*8 + jj] = W[s][c]
//   s = kstep*32 + (lane>>4)*8 + jj, c = gt*16 + (lane&15)
// kstep<16: input rows; kstep>=16: compacted source s2=s-512, zero unless
// s2<c, both <Mc, different 32-chunk (same-chunk handled by tri).
// ============================================================
__global__ __launch_bounds__(NT)
void gather2_kernel(const float* __restrict__ w, const int* __restrict__ conn,
                    const int* __restrict__ hdr, const int* __restrict__ cmap,
                    unsigned short* __restrict__ ew2) {
    const int Mc = hdr[0], nch = hdr[3], tpm = hdr[4];
    if (tpm > 64) return;                      // v1 fallback case
    const int tid  = blockIdx.x * NT + threadIdx.x;
    const int lane = tid & 63;
    const int gl   = tid >> 6;
    const int gt   = gl % tpm;
    const int kstep = gl / tpm;
    if (kstep >= 16 + nch) return;
    const int c  = gt * 16 + (lane & 15);
    const int k0 = kstep * 32 + ((lane >> 4) << 3);
    unsigned short v[8];
#pragma unroll
    for (int jj = 0; jj < 8; ++jj) {
        const int s = k0 + jj;
        float val = 0.f;
        if (c < Mc) {
            const int cc = cmap[c];
            if (s < IN_DIM) {
                const size_t o = (size_t)s * N_MID + cc;
                val = w[o] * (float)conn[o];
            } else {
                const int s2 = s - IN_DIM;
                if (s2 < Mc && s2 < c && (s2 >> 5) != (c >> 5)) {
                    const size_t o = (size_t)(IN_DIM + cmap[s2]) * N_MID + cc;
                    val = w[o] * (float)conn[o];
                }
            }
        }
        v[jj] = f2bf(val);
    }
    *(uint4*)&ew2[((size_t)(kstep * tpm + gt) * 64 + lane) * 8] = *(uint4*)v;
}

// ============================================================
// Setup C: in-chunk triangle, fp32. tri[j][sl][cl] nonzero iff sl<cl && col<Mc.
// ============================================================
__global__ __launch_bounds__(NT)
void gather_tri_kernel(const float* __restrict__ w, const int* __restrict__ conn,
                       const int* __restrict__ hdr, const int* __restrict__ cmap,
                       float* __restrict__ tri) {
    const int Mc = hdr[0], nch = hdr[3];
    const int idx = blockIdx.x * NT + threadIdx.x;   // < 32*1024
    const int j  = idx >> 10;
    if (j >= nch) return;
    const int sl = (idx >> 5) & 31;
    const int cl = idx & 31;
    const int s = j * 32 + sl, c = j * 32 + cl;
    float v = 0.f;
    if (sl < cl && c < Mc) {
        const size_t o = (size_t)(IN_DIM + cmap[s]) * N_MID + cmap[c];
        v = w[o] * (float)conn[o];
    }
    tri[idx] = v;
}

// ============================================================
// Main kernel (net5): 256 blocks x 512 threads (8 waves), 64 rows/block.
// Fragment-contiguous LDS layouts: xa[(kb*4+rr)*64+lane] and
// res2[(rr*64+lane)*8] -> lane-contiguous ds_read_b128, conflict-free.
// ============================================================
template <int TPW>
__global__ __launch_bounds__(512)
__attribute__((amdgpu_waves_per_eu(2, 2)))
void net5_kernel(const float* __restrict__ x,
                 const unsigned short* __restrict__ ew2,
                 const float* __restrict__ tri_g,
                 const int* __restrict__ hdr,
                 const int* __restrict__ ocol,
                 const float* __restrict__ biasc,
                 float* __restrict__ out) {
    if (hdr[1] != TPW * 128) return;
    const int Mc  = hdr[0];
    const int tpm = TPW * 8;                   // Mpad/16
    const int nch = TPW * 4;                   // Mpad/32

    __shared__ __align__(16) unsigned short xa[4096 * 8];      // 65,536 B
    __shared__ float stage[64 * 33];                           //  8,448 B
    __shared__ __align__(16) unsigned short res2[2][2048];     //  8,192 B
    __shared__ __align__(16) float tri_lds[2][1024];           //  8,192 B
    __shared__ float bias_lds[1024];                           //  4,096 B
    __shared__ int   ocol_lds[1024];                           //  4,096 B
    // total ~98.5 KB -> 1 block/CU -> 2 waves/SIMD -> 256-reg budget

    const int t = threadIdx.x, lane = t & 63, w = t >> 6;  // w in 0..7
    const int l15 = lane & 15, q = lane >> 4;
    const int r0 = blockIdx.x * 64;
    const int g0 = w * TPW;

    // ---- stage bias/ocol ----
    for (int i = t; i < TPW * 128; i += 512) {
        bias_lds[i] = biasc[i];
        ocol_lds[i] = ocol[i];
    }
    // ---- tri chunk 0 (wave 7) ----
    if (w == 7) {
        const float4* src = (const float4*)tri_g;
#pragma unroll
        for (int u = 0; u < 4; ++u)
            *(float4*)&tri_lds[0][(lane + 64 * u) * 4] = src[lane + 64 * u];
    }
    // ---- x -> bf16 A-fragment-contiguous: frag i=(kb*4+rr)*64+lane2 ----
    for (int i = t; i < 4096; i += 512) {
        const int lane2 = i & 63, rrkb = i >> 6;
        const int rr = rrkb & 3, kb = rrkb >> 2;
        const int qq = lane2 >> 4, ll = lane2 & 15;
        const int row = rr * 16 + ll;
        const int k0 = kb * 32 + qq * 8;
        const float4 f0 = *(const float4*)&x[(size_t)(r0 + row) * IN_DIM + k0];
        const float4 f1 = *(const float4*)&x[(size_t)(r0 + row) * IN_DIM + k0 + 4];
        unsigned short vv[8] = {f2bf(f0.x), f2bf(f0.y), f2bf(f0.z), f2bf(f0.w),
                                f2bf(f1.x), f2bf(f1.y), f2bf(f1.z), f2bf(f1.w)};
        *(uint4*)&xa[(size_t)i * 8] = *(uint4*)vv;
    }
    __syncthreads();

    ffrag acc[TPW][4];
#pragma unroll
    for (int tt = 0; tt < TPW; ++tt)
#pragma unroll
        for (int rr = 0; rr < 4; ++rr) acc[tt][rr] = (ffrag)0.f;

    // ---- phase 1: input GEMM, 16 k-steps ----
#pragma unroll 1
    for (int kb = 0; kb < 16; ++kb) {
        bfrag a[4];
#pragma unroll
        for (int rr = 0; rr < 4; ++rr)
            a[rr] = *(const bfrag*)&xa[((kb * 4 + rr) * 64 + lane) * 8];
#pragma unroll
        for (int tt = 0; tt < TPW; ++tt) {
            if ((g0 + tt) * 16 < Mc) {
                const bfrag b = *(const bfrag*)&ew2[((size_t)(kb * tpm + g0 + tt) * 64 + lane) * 8];
#pragma unroll
                for (int rr = 0; rr < 4; ++rr)
                    acc[tt][rr] = __builtin_amdgcn_mfma_f32_16x16x32_bf16(a[rr], b, acc[tt][rr], 0, 0, 0);
            }
        }
    }

    // ---- phase 2: sequential chunks ----
#pragma unroll 1
    for (int j = 0; j < nch; ++j) {
        const int cbase = 32 * j;
        if (cbase >= Mc) break;                      // uniform

        if (j > 0) {                                 // apply res_{j-1}
            const int pr = (j - 1) & 1;
            bfrag a[4];
#pragma unroll
            for (int rr = 0; rr < 4; ++rr)
                a[rr] = *(const bfrag*)&res2[pr][(rr * 64 + lane) * 8];
#pragma unroll
            for (int tt = 0; tt < TPW; ++tt) {
                const int col0 = (g0 + tt) * 16;
                if (col0 >= cbase && col0 < Mc) {
                    const bfrag b = *(const bfrag*)&ew2[((size_t)((15 + j) * tpm + g0 + tt) * 64 + lane) * 8];
#pragma unroll
                    for (int rr = 0; rr < 4; ++rr)
                        acc[tt][rr] = __builtin_amdgcn_mfma_f32_16x16x32_bf16(a[rr], b, acc[tt][rr], 0, 0, 0);
                }
            }
        }

        // stage chunk tiles (C-layout -> [row][col])
#pragma unroll
        for (int tt = 0; tt < TPW; ++tt) {
            const int g = g0 + tt;
            if (g == 2 * j || g == 2 * j + 1) {
                const int half = (g & 1) ? 16 : 0;
#pragma unroll
                for (int rr = 0; rr < 4; ++rr)
#pragma unroll
                    for (int r = 0; r < 4; ++r)
                        stage[(rr * 16 + 4 * q + r) * 33 + half + l15] = acc[tt][rr][r];
            }
        }
        __syncthreads();                             // A

        const int rsv = j & 7;
        if (w == rsv) {
            // transposed resolve: lane = batch row; two 16-col halves
            const float* trij = tri_lds[j & 1];
            unsigned short* resb = res2[j & 1];
            const int rrL = lane >> 4, l15L = lane & 15;
            float rs0[16];
            {   // half 0: cols 0..15
                float reg[16];
#pragma unroll
                for (int c = 0; c < 16; ++c) reg[c] = stage[lane * 33 + c];
#pragma unroll
                for (int c = 0; c < 16; ++c) {
                    const float s  = __fdividef(1.f, 1.f + __expf(-reg[c]));
                    const float rs = s + bias_lds[cbase + c];
                    rs0[c] = rs;
                    resb[(rrL * 64 + (c >> 3) * 16 + l15L) * 8 + (c & 7)] = f2bf(rs);
                    const int oc = ocol_lds[cbase + c];
                    if (oc >= 0)
                        out[(size_t)(r0 + lane) * OUT_DIM + oc] = rs;
#pragma unroll
                    for (int k = c + 1; k < 16; ++k)
                        reg[k] = fmaf(rs, trij[c * 32 + k], reg[k]);
                }
            }
            {   // half 1: cols 16..31 (cross-half via fp32 rs0)
                float reg[16];
#pragma unroll
                for (int k = 0; k < 16; ++k) reg[k] = stage[lane * 33 + 16 + k];
#pragma unroll
                for (int c = 0; c < 16; ++c) {
#pragma unroll
                    for (int k = 0; k < 16; ++k)
                        reg[k] = fmaf(rs0[c], trij[c * 32 + 16 + k], reg[k]);
                }
#pragma unroll
                for (int c = 0; c < 16; ++c) {
                    const float s  = __fdividef(1.f, 1.f + __expf(-reg[c]));
                    const float rs = s + bias_lds[cbase + 16 + c];
                    resb[(rrL * 64 + (2 + (c >> 3)) * 16 + l15L) * 8 + (c & 7)] = f2bf(rs);
                    const int oc = ocol_lds[cbase + 16 + c];
                    if (oc >= 0)
                        out[(size_t)(r0 + lane) * OUT_DIM + oc] = rs;
#pragma unroll
                    for (int k = c + 1; k < 16; ++k)
                        reg[k] = fmaf(rs, trij[(16 + c) * 32 + 16 + k], reg[k]);
                }
            }
        } else if (w == ((rsv + 4) & 7)) {
            // prefetch tri for chunk j+1 (overlapped with resolve)
            const int jn = j + 1;
            if (jn < nch && 32 * jn < Mc) {
                const float4* src = (const float4*)(tri_g + (size_t)jn * 1024);
#pragma unroll
                for (int u = 0; u < 4; ++u)
                    *(float4*)&tri_lds[jn & 1][(lane + 64 * u) * 4] = src[lane + 64 * u];
            }
        }
        __syncthreads();                             // B
    }
}

// ============================================================
// Fallback (Mc > 1024 or tiny ws): round-1 monolithic fp32 kernel.
// ============================================================
__global__ __launch_bounds__(NT, 4)
void net_v1_kernel(const float* __restrict__ x,
                   const float* __restrict__ wsrc,
                   const int* __restrict__ conn,
                   const float* __restrict__ bias,
                   const int* __restrict__ exist,
                   const int* __restrict__ hdr,   // null = always run
                   float* __restrict__ out) {
    if (hdr && hdr[1] <= 1024) return;
    __shared__ float xs[16 * XPAD];
    __shared__ float res_s[2][16];
    float* bias_s  = xs;
    float* exist_s = xs + N_MID;
    const int t = threadIdx.x, rg = t & 3, cg = t >> 2;
    const int r0 = blockIdx.x * 16;
    const int c0 = cg * 20;
    {
        const float4* xg = (const float4*)(x + (size_t)r0 * IN_DIM);
        for (int idx = t; idx < 16 * IN_DIM / 4; idx += NT) {
            const int r = idx >> 7, jj = idx & 127;
            *(float4*)&xs[r * XPAD + jj * 4] = xg[idx];
        }
    }
    __syncthreads();
    float acc[4][20];
#pragma unroll
    for (int a = 0; a < 4; ++a)
#pragma unroll
        for (int k = 0; k < 20; ++k) acc[a][k] = 0.f;
    for (int j = 0; j < IN_DIM; ++j) {
        const size_t woff = (size_t)j * N_MID + c0;
        const float xv0 = xs[rg * XPAD + j];
        const float xv1 = xs[(rg + 4) * XPAD + j];
        const float xv2 = xs[(rg + 8) * XPAD + j];
        const float xv3 = xs[(rg + 12) * XPAD + j];
#pragma unroll
        for (int qq = 0; qq < 5; ++qq) {
            float4 w4 = *(const float4*)(wsrc + woff + qq * 4);
            const int4 c4 = *(const int4*)(conn + woff + qq * 4);
            w4.x *= (float)c4.x; w4.y *= (float)c4.y;
            w4.z *= (float)c4.z; w4.w *= (float)c4.w;
            const float wq[4] = {w4.x, w4.y, w4.z, w4.w};
#pragma unroll
            for (int u = 0; u < 4; ++u) {
                const int k = qq * 4 + u;
                acc[0][k] = fmaf(xv0, wq[u], acc[0][k]);
                acc[1][k] = fmaf(xv1, wq[u], acc[1][k]);
                acc[2][k] = fmaf(xv2, wq[u], acc[2][k]);
                acc[3][k] = fmaf(xv3, wq[u], acc[3][k]);
            }
        }
    }
    __syncthreads();
    for (int idx = t; idx < N_MID; idx += NT) {
        bias_s[idx]  = bias[idx];
        exist_s[idx] = (float)exist[idx];
    }
    __syncthreads();
    int p = 0;
    for (int bb = 0; bb < 64; ++bb) {
#pragma unroll
        for (int kk = 0; kk < 20; ++kk) {
            const int i = bb * 20 + kk;
            const float e = exist_s[i];
            if (e != 0.f) {
                if (cg == bb) {
                    const float bv = bias_s[i];
#pragma unroll
                    for (int a = 0; a < 4; ++a) {
                        const float v = acc[a][kk];
                        const float s = __fdividef(1.f, 1.f + __expf(-v));
                        const float res = (s + bv) * e;
                        res_s[p][rg + 4 * a] = res;
                        if (i >= N_MID - OUT_DIM)
                            out[(size_t)(r0 + rg + 4 * a) * OUT_DIM + (i - (N_MID - OUT_DIM))] = res;
                    }
                }
                __syncthreads();
                const float rv0 = res_s[p][rg];
                const float rv1 = res_s[p][rg + 4];
                const float rv2 = res_s[p][rg + 8];
                const float rv3 = res_s[p][rg + 12];
                const size_t woff = (size_t)(IN_DIM + i) * N_MID + c0;
                if (cg > bb) {
#pragma unroll
                    for (int qq = 0; qq < 5; ++qq) {
                        float4 w4 = *(const float4*)(wsrc + woff + qq * 4);
                        const int4 c4 = *(const int4*)(conn + woff + qq * 4);
                        w4.x *= (float)c4.x; w4.y *= (float)c4.y;
                        w4.z *= (float)c4.z; w4.w *= (float)c4.w;
                        const float wq[4] = {w4.x, w4.y, w4.z, w4.w};
#pragma unroll
                        for (int u = 0; u < 4; ++u) {
                            const int k = qq * 4 + u;
                            acc[0][k] = fmaf(rv0, wq[u], acc[0][k]);
                            acc[1][k] = fmaf(rv1, wq[u], acc[1][k]);
                            acc[2][k] = fmaf(rv2, wq[u], acc[2][k]);
                            acc[3][k] = fmaf(rv3, wq[u], acc[3][k]);
                        }
                    }
                } else if (cg == bb) {
#pragma unroll
                    for (int k = kk + 1; k < 20; ++k) {
                        float ww = wsrc[woff + k] * (float)conn[woff + k];
                        acc[0][k] = fmaf(rv0, ww, acc[0][k]);
                        acc[1][k] = fmaf(rv1, ww, acc[1][k]);
                        acc[2][k] = fmaf(rv2, ww, acc[2][k]);
                        acc[3][k] = fmaf(rv3, ww, acc[3][k]);
                    }
                }
                p ^= 1;
            }
        }
    }
}

extern "C" void kernel_launch(void* const* d_in, const int* in_sizes, int n_in,
                              void* d_out, int out_size, void* d_ws, size_t ws_size,
                              hipStream_t stream) {
    const float* x      = (const float*)d_in[0];
    const float* weight = (const float*)d_in[1];
    const float* bias   = (const float*)d_in[2];
    const int*   conn   = (const int*)d_in[3];
    const int*   exist  = (const int*)d_in[4];
    float*       out    = (float*)d_out;

    if (ws_size >= WS_NEED) {
        char* ws = (char*)d_ws;
        unsigned short* ew2  = (unsigned short*)ws;
        float*          tri  = (float*)(ws + TRI_OFF);
        int*            hdr  = (int*)(ws + HDR_OFF);
        int*            cmap = (int*)(ws + CMAP_OFF);
        int*            ocolp= (int*)(ws + OCOL_OFF);
        float*          bsc  = (float*)(ws + BIASC_OFF);

        build_maps_kernel<<<1, 64, 0, stream>>>(exist, bias, hdr, cmap, ocolp, bsc);
        gather2_kernel<<<768, NT, 0, stream>>>(weight, conn, hdr, cmap, ew2);
        gather_tri_kernel<<<128, NT, 0, stream>>>(weight, conn, hdr, cmap, tri);
        net5_kernel<6><<<BATCH / 64, 512, 0, stream>>>(x, ew2, tri, hdr, ocolp, bsc, out);
        net5_kernel<8><<<BATCH / 64, 512, 0, stream>>>(x, ew2, tri, hdr, ocolp, bsc, out);
        net_v1_kernel<<<BATCH / 16, NT, 0, stream>>>(x, weight, conn, bias, exist, hdr, out);
    } else {
        net_v1_kernel<<<BATCH / 16, NT, 0, stream>>>(x, weight, conn, bias, exist, nullptr, out);
    }
}

// Round 8
// 356.973 us; speedup vs baseline: 2.6380x; 1.0227x over previous
//
#include <hip/hip_runtime.h>

#define IN_DIM   512
#define OUT_DIM  256
#define N_MID    1280
#define BATCH    16384
#define NT       256
#define XPAD     520      // fallback kernel x stride

// net6 geometry: 256 blocks x 256 threads (4 waves), 64 rows/block, 1 block/CU
// -> 1 wave/SIMD -> ~512-reg unified budget per wave (m69: no spill til ~450).
// R4-R7 lesson: every prior config spilled (scratch HBM traffic == wall time).
// Wave w owns TPW col-tiles x 4 row-groups (acc[TPW][4] ffrags <= 256 accum).
// Owner wave of chunk j (tiles 2j,2j+1) stages its tiles to LDS and resolves
// them in-wave (LDS ops in-order within a wave) -> ONE barrier per chunk.

// ---- workspace layout (max geometry: ksteps=48, tpm=64, nch=32) ----
#define EW2_ELEMS ((size_t)48 * 64 * 64 * 8)               // bf16 elems
#define EW2_BYTES (EW2_ELEMS * 2)                          // 3,145,728
#define TRI_OFF   EW2_BYTES
#define TRI_BYTES ((size_t)32 * 1024 * 4)                  // 131,072
#define HDR_OFF   (TRI_OFF + TRI_BYTES)
#define CMAP_OFF  (HDR_OFF + 32)
#define OCOL_OFF  (CMAP_OFF + N_MID * 4)
#define BIASC_OFF (OCOL_OFF + N_MID * 4)
#define WS_NEED   (BIASC_OFF + N_MID * 4)

typedef __attribute__((ext_vector_type(8))) short  bfrag;
typedef __attribute__((ext_vector_type(4))) float  ffrag;

__device__ __forceinline__ unsigned short f2bf(float f) {
    unsigned int u = __float_as_uint(f);
    u += 0x7FFFu + ((u >> 16) & 1u);       // RNE
    return (unsigned short)(u >> 16);
}

// ============================================================
// Setup A: compact existing columns (1 wave).
// hdr = {Mc, Mpad, unused, nch=Mpad/32, tpm=Mpad/16}
// ============================================================
__global__ void build_maps_kernel(const int* __restrict__ exist,
                                  const float* __restrict__ bias,
                                  int* __restrict__ hdr,
                                  int* __restrict__ cmap,
                                  int* __restrict__ ocol,
                                  float* __restrict__ biasc) {
    const int lane = threadIdx.x;   // 64
    int base = 0;
    for (int r = 0; r < N_MID / 64; ++r) {
        const int i = r * 64 + lane;
        const int e = exist[i];
        const unsigned long long m  = __ballot(e != 0);
        const unsigned long long lt = (lane == 0) ? 0ull : (~0ull >> (64 - lane));
        const int pos = base + __popcll(m & lt);
        if (e) {
            cmap[pos]  = i;
            ocol[pos]  = (i >= N_MID - OUT_DIM) ? (i - (N_MID - OUT_DIM)) : -1;
            biasc[pos] = bias[i];
        }
        base += __popcll(m);
    }
    for (int idx = base + lane; idx < N_MID; idx += 64) {
        cmap[idx] = 0; ocol[idx] = -1; biasc[idx] = 0.f;
    }
    if (lane == 0) {
        const int Mc = base;
        int Mpad;
        if (Mc <= 768) Mpad = 768;
        else if (Mc <= 1024) Mpad = 1024;
        else Mpad = (Mc + 127) & ~127;     // v1 fallback territory
        hdr[0] = Mc; hdr[1] = Mpad; hdr[2] = 0;
        hdr[3] = Mpad / 32; hdr[4] = Mpad / 16;
    }
}

// ============================================================
// Setup B: gather eff_w -> bf16 MFMA B-fragment-major.
// ew2[((kstep*tpm + gt)*64 + lane)*8 + jj] = W[s][c]
//   s = kstep*32 + (lane>>4)*8 + jj, c = gt*16 + (lane&15)
// kstep<16: input rows; kstep>=16: compacted source s2=s-512, zero unless
// s2<c, both <Mc, different 32-chunk (same-chunk handled by tri).
// ============================================================
__global__ __launch_bounds__(NT)
void gather2_kernel(const float* __restrict__ w, const int* __restrict__ conn,
                    const int* __restrict__ hdr, const int* __restrict__ cmap,
                    unsigned short* __restrict__ ew2) {
    const int Mc = hdr[0], nch = hdr[3], tpm = hdr[4];
    if (tpm > 64) return;                      // v1 fallback case
    const int tid  = blockIdx.x * NT + threadIdx.x;
    const int lane = tid & 63;
    const int gl   = tid >> 6;
    const int gt   = gl % tpm;
    const int kstep = gl / tpm;
    if (kstep >= 16 + nch) return;
    const int c  = gt * 16 + (lane & 15);
    const int k0 = kstep * 32 + ((lane >> 4) << 3);
    unsigned short v[8];
#pragma unroll
    for (int jj = 0; jj < 8; ++jj) {
        const int s = k0 + jj;
        float val = 0.f;
        if (c < Mc) {
            const int cc = cmap[c];
            if (s < IN_DIM) {
                const size_t o = (size_t)s * N_MID + cc;
                val = w[o] * (float)conn[o];
            } else {
                const int s2 = s - IN_DIM;
                if (s2 < Mc && s2 < c && (s2 >> 5) != (c >> 5)) {
                    const size_t o = (size_t)(IN_DIM + cmap[s2]) * N_MID + cc;
                    val = w[o] * (float)conn[o];
                }
            }
        }
        v[jj] = f2bf(val);
    }
    *(uint4*)&ew2[((size_t)(kstep * tpm + gt) * 64 + lane) * 8] = *(uint4*)v;
}

// ============================================================
// Setup C: in-chunk triangle, fp32. tri[j][sl][cl] nonzero iff sl<cl && col<Mc.
// ============================================================
__global__ __launch_bounds__(NT)
void gather_tri_kernel(const float* __restrict__ w, const int* __restrict__ conn,
                       const int* __restrict__ hdr, const int* __restrict__ cmap,
                       float* __restrict__ tri) {
    const int Mc = hdr[0], nch = hdr[3];
    const int idx = blockIdx.x * NT + threadIdx.x;   // < 32*1024
    const int j  = idx >> 10;
    if (j >= nch) return;
    const int sl = (idx >> 5) & 31;
    const int cl = idx & 31;
    const int s = j * 32 + sl, c = j * 32 + cl;
    float v = 0.f;
    if (sl < cl && c < Mc) {
        const size_t o = (size_t)(IN_DIM + cmap[s]) * N_MID + cmap[c];
        v = w[o] * (float)conn[o];
    }
    tri[idx] = v;
}

// ============================================================
// Main kernel (net6): 256 blocks x 256 threads (4 waves), 64 rows/block.
// Mpad = TPW*64 (TPW tiles/wave x 4 waves x 16 cols). One barrier per chunk.
// ============================================================
template <int TPW>
__global__ __launch_bounds__(256)
__attribute__((amdgpu_waves_per_eu(1, 1)))
void net6_kernel(const float* __restrict__ x,
                 const unsigned short* __restrict__ ew2,
                 const float* __restrict__ tri_g,
                 const int* __restrict__ hdr,
                 const int* __restrict__ ocol,
                 const float* __restrict__ biasc,
                 float* __restrict__ out) {
    if (hdr[1] != TPW * 64) return;
    const int Mc  = hdr[0];
    const int tpm = TPW * 4;                   // Mpad/16
    const int nch = TPW * 2;                   // Mpad/32

    __shared__ __align__(16) unsigned short xa[4096 * 8];      // 65,536 B
    __shared__ float stage[64 * 33];                           //  8,448 B
    __shared__ __align__(16) unsigned short res2[2][2048];     //  8,192 B
    __shared__ __align__(16) float tri_lds[2][1024];           //  8,192 B
    __shared__ float bias_lds[1024];                           //  4,096 B
    __shared__ int   ocol_lds[1024];                           //  4,096 B
    // total ~98.5 KB -> 1 block/CU; 4 waves -> 1 wave/SIMD -> ~512-reg budget

    const int t = threadIdx.x, lane = t & 63, w = t >> 6;  // w in 0..3
    const int l15 = lane & 15, q = lane >> 4;
    const int r0 = blockIdx.x * 64;
    const int g0 = w * TPW;

    // ---- stage bias/ocol ----
    for (int i = t; i < TPW * 64; i += 256) {
        bias_lds[i] = biasc[i];
        ocol_lds[i] = ocol[i];
    }
    // ---- tri chunk 0 (wave 3) ----
    if (w == 3) {
        const float4* src = (const float4*)tri_g;
#pragma unroll
        for (int u = 0; u < 4; ++u)
            *(float4*)&tri_lds[0][(lane + 64 * u) * 4] = src[lane + 64 * u];
    }
    // ---- x -> bf16 A-fragment-contiguous: frag i = (kb*4+rr)*64 + lane2 ----
    for (int i = t; i < 4096; i += 256) {
        const int lane2 = i & 63, rrkb = i >> 6;
        const int rr = rrkb & 3, kb = rrkb >> 2;
        const int qq = lane2 >> 4, ll = lane2 & 15;
        const int row = rr * 16 + ll;
        const int k0 = kb * 32 + qq * 8;
        const float4 f0 = *(const float4*)&x[(size_t)(r0 + row) * IN_DIM + k0];
        const float4 f1 = *(const float4*)&x[(size_t)(r0 + row) * IN_DIM + k0 + 4];
        unsigned short vv[8] = {f2bf(f0.x), f2bf(f0.y), f2bf(f0.z), f2bf(f0.w),
                                f2bf(f1.x), f2bf(f1.y), f2bf(f1.z), f2bf(f1.w)};
        *(uint4*)&xa[(size_t)i * 8] = *(uint4*)vv;
    }
    __syncthreads();

    ffrag acc[TPW][4];
#pragma unroll
    for (int tt = 0; tt < TPW; ++tt)
#pragma unroll
        for (int rr = 0; rr < 4; ++rr) acc[tt][rr] = (ffrag)0.f;

    // ---- phase 1: input GEMM, 16 k-steps ----
#pragma unroll 1
    for (int kb = 0; kb < 16; ++kb) {
        bfrag a[4];
#pragma unroll
        for (int rr = 0; rr < 4; ++rr)
            a[rr] = *(const bfrag*)&xa[((kb * 4 + rr) * 64 + lane) * 8];
#pragma unroll
        for (int tt = 0; tt < TPW; ++tt) {
            if ((g0 + tt) * 16 < Mc) {
                const bfrag b = *(const bfrag*)&ew2[((size_t)(kb * tpm + g0 + tt) * 64 + lane) * 8];
#pragma unroll
                for (int rr = 0; rr < 4; ++rr)
                    acc[tt][rr] = __builtin_amdgcn_mfma_f32_16x16x32_bf16(a[rr], b, acc[tt][rr], 0, 0, 0);
            }
        }
    }

    // ---- phase 2: sequential chunks, ONE barrier each ----
#pragma unroll 1
    for (int j = 0; j < nch; ++j) {
        const int cbase = 32 * j;
        if (cbase >= Mc) break;                      // uniform

        if (j > 0) {                                 // apply res_{j-1}
            const int pr = (j - 1) & 1;
            bfrag a[4];
#pragma unroll
            for (int rr = 0; rr < 4; ++rr)
                a[rr] = *(const bfrag*)&res2[pr][(rr * 64 + lane) * 8];
#pragma unroll
            for (int tt = 0; tt < TPW; ++tt) {
                const int col0 = (g0 + tt) * 16;
                if (col0 >= cbase && col0 < Mc) {
                    const bfrag b = *(const bfrag*)&ew2[((size_t)((15 + j) * tpm + g0 + tt) * 64 + lane) * 8];
#pragma unroll
                    for (int rr = 0; rr < 4; ++rr)
                        acc[tt][rr] = __builtin_amdgcn_mfma_f32_16x16x32_bf16(a[rr], b, acc[tt][rr], 0, 0, 0);
                }
            }
        }

        const int ow = (2 * j) / TPW;                // owner wave (tiles 2j, 2j+1)
        if (w == ow) {
            // stage own chunk tiles (C-layout -> [row][col]), in-wave
#pragma unroll
            for (int tt = 0; tt < TPW; ++tt) {
                const int g = g0 + tt;
                if (g == 2 * j || g == 2 * j + 1) {
                    const int half = (g & 1) ? 16 : 0;
#pragma unroll
                    for (int rr = 0; rr < 4; ++rr)
#pragma unroll
                        for (int r = 0; r < 4; ++r)
                            stage[(rr * 16 + 4 * q + r) * 33 + half + l15] = acc[tt][rr][r];
                }
            }
            // transposed resolve: lane = batch row, full fp32 reg[32]
            const float* trij = tri_lds[j & 1];
            unsigned short* resb = res2[j & 1];
            const int rrL = lane >> 4, l15L = lane & 15;
            float reg[32];
#pragma unroll
            for (int c = 0; c < 32; ++c) reg[c] = stage[lane * 33 + c];
#pragma unroll
            for (int c = 0; c < 32; ++c) {
                const float s  = __fdividef(1.f, 1.f + __expf(-reg[c]));
                const float rs = s + bias_lds[cbase + c];
                resb[(rrL * 64 + (c >> 3) * 16 + l15L) * 8 + (c & 7)] = f2bf(rs);
                const int oc = ocol_lds[cbase + c];           // uniform
                if (oc >= 0)
                    out[(size_t)(r0 + lane) * OUT_DIM + oc] = rs;
#pragma unroll
                for (int k = c + 1; k < 32; ++k)
                    reg[k] = fmaf(rs, trij[c * 32 + k], reg[k]);
            }
        } else if (w == ((ow + 2) & 3)) {
            // prefetch tri for chunk j+1 (overlaps resolve)
            const int jn = j + 1;
            if (jn < nch && 32 * jn < Mc) {
                const float4* src = (const float4*)(tri_g + (size_t)jn * 1024);
#pragma unroll
                for (int u = 0; u < 4; ++u)
                    *(float4*)&tri_lds[jn & 1][(lane + 64 * u) * 4] = src[lane + 64 * u];
            }
        }
        __syncthreads();                             // the ONE barrier
    }
}

// ============================================================
// Fallback (Mc > 1024 or tiny ws): round-1 monolithic fp32 kernel.
// ============================================================
__global__ __launch_bounds__(NT, 4)
void net_v1_kernel(const float* __restrict__ x,
                   const float* __restrict__ wsrc,
                   const int* __restrict__ conn,
                   const float* __restrict__ bias,
                   const int* __restrict__ exist,
                   const int* __restrict__ hdr,   // null = always run
                   float* __restrict__ out) {
    if (hdr && hdr[1] <= 1024) return;
    __shared__ float xs[16 * XPAD];
    __shared__ float res_s[2][16];
    float* bias_s  = xs;
    float* exist_s = xs + N_MID;
    const int t = threadIdx.x, rg = t & 3, cg = t >> 2;
    const int r0 = blockIdx.x * 16;
    const int c0 = cg * 20;
    {
        const float4* xg = (const float4*)(x + (size_t)r0 * IN_DIM);
        for (int idx = t; idx < 16 * IN_DIM / 4; idx += NT) {
            const int r = idx >> 7, jj = idx & 127;
            *(float4*)&xs[r * XPAD + jj * 4] = xg[idx];
        }
    }
    __syncthreads();
    float acc[4][20];
#pragma unroll
    for (int a = 0; a < 4; ++a)
#pragma unroll
        for (int k = 0; k < 20; ++k) acc[a][k] = 0.f;
    for (int j = 0; j < IN_DIM; ++j) {
        const size_t woff = (size_t)j * N_MID + c0;
        const float xv0 = xs[rg * XPAD + j];
        const float xv1 = xs[(rg + 4) * XPAD + j];
        const float xv2 = xs[(rg + 8) * XPAD + j];
        const float xv3 = xs[(rg + 12) * XPAD + j];
#pragma unroll
        for (int qq = 0; qq < 5; ++qq) {
            float4 w4 = *(const float4*)(wsrc + woff + qq * 4);
            const int4 c4 = *(const int4*)(conn + woff + qq * 4);
            w4.x *= (float)c4.x; w4.y *= (float)c4.y;
            w4.z *= (float)c4.z; w4.w *= (float)c4.w;
            const float wq[4] = {w4.x, w4.y, w4.z, w4.w};
#pragma unroll
            for (int u = 0; u < 4; ++u) {
                const int k = qq * 4 + u;
                acc[0][k] = fmaf(xv0, wq[u], acc[0][k]);
                acc[1][k] = fmaf(xv1, wq[u], acc[1][k]);
                acc[2][k] = fmaf(xv2, wq[u], acc[2][k]);
                acc[3][k] = fmaf(xv3, wq[u], acc[3][k]);
            }
        }
    }
    __syncthreads();
    for (int idx = t; idx < N_MID; idx += NT) {
        bias_s[idx]  = bias[idx];
        exist_s[idx] = (float)exist[idx];
    }
    __syncthreads();
    int p = 0;
    for (int bb = 0; bb < 64; ++bb) {
#pragma unroll
        for (int kk = 0; kk < 20; ++kk) {
            const int i = bb * 20 + kk;
            const float e = exist_s[i];
            if (e != 0.f) {
                if (cg == bb) {
                    const float bv = bias_s[i];
#pragma unroll
                    for (int a = 0; a < 4; ++a) {
                        const float v = acc[a][kk];
                        const float s = __fdividef(1.f, 1.f + __expf(-v));
                        const float res = (s + bv) * e;
                        res_s[p][rg + 4 * a] = res;
                        if (i >= N_MID - OUT_DIM)
                            out[(size_t)(r0 + rg + 4 * a) * OUT_DIM + (i - (N_MID - OUT_DIM))] = res;
                    }
                }
                __syncthreads();
                const float rv0 = res_s[p][rg];
                const float rv1 = res_s[p][rg + 4];
                const float rv2 = res_s[p][rg + 8];
                const float rv3 = res_s[p][rg + 12];
                const size_t woff = (size_t)(IN_DIM + i) * N_MID + c0;
                if (cg > bb) {
#pragma unroll
                    for (int qq = 0; qq < 5; ++qq) {
                        float4 w4 = *(const float4*)(wsrc + woff + qq * 4);
                        const int4 c4 = *(const int4*)(conn + woff + qq * 4);
                        w4.x *= (float)c4.x; w4.y *= (float)c4.y;
                        w4.z *= (float)c4.z; w4.w *= (float)c4.w;
                        const float wq[4] = {w4.x, w4.y, w4.z, w4.w};
#pragma unroll
                        for (int u = 0; u < 4; ++u) {
                            const int k = qq * 4 + u;
                            acc[0][k] = fmaf(rv0, wq[u], acc[0][k]);
                            acc[1][k] = fmaf(rv1, wq[u], acc[1][k]);
                            acc[2][k] = fmaf(rv2, wq[u], acc[2][k]);
                            acc[3][k] = fmaf(rv3, wq[u], acc[3][k]);
                        }
                    }
                } else if (cg == bb) {
#pragma unroll
                    for (int k = kk + 1; k < 20; ++k) {
                        float ww = wsrc[woff + k] * (float)conn[woff + k];
                        acc[0][k] = fmaf(rv0, ww, acc[0][k]);
                        acc[1][k] = fmaf(rv1, ww, acc[1][k]);
                        acc[2][k] = fmaf(rv2, ww, acc[2][k]);
                        acc[3][k] = fmaf(rv3, ww, acc[3][k]);
                    }
                }
                p ^= 1;
            }
        }
    }
}

extern "C" void kernel_launch(void* const* d_in, const int* in_sizes, int n_in,
                              void* d_out, int out_size, void* d_ws, size_t ws_size,
                              hipStream_t stream) {
    const float* x      = (const float*)d_in[0];
    const float* weight = (const float*)d_in[1];
    const float* bias   = (const float*)d_in[2];
    const int*   conn   = (const int*)d_in[3];
    const int*   exist  = (const int*)d_in[4];
    float*       out    = (float*)d_out;

    if (ws_size >= WS_NEED) {
        char* ws = (char*)d_ws;
        unsigned short* ew2  = (unsigned short*)ws;
        float*          tri  = (float*)(ws + TRI_OFF);
        int*            hdr  = (int*)(ws + HDR_OFF);
        int*            cmap = (int*)(ws + CMAP_OFF);
        int*            ocolp= (int*)(ws + OCOL_OFF);
        float*          bsc  = (float*)(ws + BIASC_OFF);

        build_maps_kernel<<<1, 64, 0, stream>>>(exist, bias, hdr, cmap, ocolp, bsc);
        gather2_kernel<<<768, NT, 0, stream>>>(weight, conn, hdr, cmap, ew2);
        gather_tri_kernel<<<128, NT, 0, stream>>>(weight, conn, hdr, cmap, tri);
        net6_kernel<12><<<256, 256, 0, stream>>>(x, ew2, tri, hdr, ocolp, bsc, out);
        net6_kernel<16><<<256, 256, 0, stream>>>(x, ew2, tri, hdr, ocolp, bsc, out);
        net_v1_kernel<<<BATCH / 16, NT, 0, stream>>>(x, weight, conn, bias, exist, hdr, out);
    } else {
        net_v1_kernel<<<BATCH / 16, NT, 0, stream>>>(x, weight, conn, bias, exist, nullptr, out);
    }
}

// Round 9
// 352.488 us; speedup vs baseline: 2.6716x; 1.0127x over previous
//
#include <hip/hip_runtime.h>

#define IN_DIM   512
#define OUT_DIM  256
#define N_MID    1280
#define BATCH    16384
#define NT       256
#define XPAD     520      // fallback kernel x stride

// net7 geometry: 256 blocks x 256 threads (4 waves), 64 rows/block, 1 block/CU,
// 1 wave/SIMD -> ~512-reg unified budget (R8: VGPR=256, zero spill traffic).
// R8 lesson: wall = phase-2 serial chain (~890 cyc/node), NOT bandwidth.
// R9 changes: tri rows reg-prefetched (b128, 1 node ahead), b128 staging,
// bulk res2/out writes -> no memory hop left on the per-node dependent chain.

// ---- workspace layout (max geometry: ksteps=48, tpm=64, nch=32) ----
#define EW2_ELEMS ((size_t)48 * 64 * 64 * 8)               // bf16 elems
#define EW2_BYTES (EW2_ELEMS * 2)                          // 3,145,728
#define TRI_OFF   EW2_BYTES
#define TRI_BYTES ((size_t)32 * 1024 * 4)                  // 131,072
#define HDR_OFF   (TRI_OFF + TRI_BYTES)
#define CMAP_OFF  (HDR_OFF + 32)
#define OCOL_OFF  (CMAP_OFF + N_MID * 4)
#define BIASC_OFF (OCOL_OFF + N_MID * 4)
#define WS_NEED   (BIASC_OFF + N_MID * 4)

typedef __attribute__((ext_vector_type(8))) short  bfrag;
typedef __attribute__((ext_vector_type(4))) float  ffrag;

__device__ __forceinline__ unsigned short f2bf(float f) {
    unsigned int u = __float_as_uint(f);
    u += 0x7FFFu + ((u >> 16) & 1u);       // RNE
    return (unsigned short)(u >> 16);
}

// ============================================================
// Setup A: compact existing columns (1 wave).
// hdr = {Mc, Mpad, unused, nch=Mpad/32, tpm=Mpad/16}
// ============================================================
__global__ void build_maps_kernel(const int* __restrict__ exist,
                                  const float* __restrict__ bias,
                                  int* __restrict__ hdr,
                                  int* __restrict__ cmap,
                                  int* __restrict__ ocol,
                                  float* __restrict__ biasc) {
    const int lane = threadIdx.x;   // 64
    int base = 0;
    for (int r = 0; r < N_MID / 64; ++r) {
        const int i = r * 64 + lane;
        const int e = exist[i];
        const unsigned long long m  = __ballot(e != 0);
        const unsigned long long lt = (lane == 0) ? 0ull : (~0ull >> (64 - lane));
        const int pos = base + __popcll(m & lt);
        if (e) {
            cmap[pos]  = i;
            ocol[pos]  = (i >= N_MID - OUT_DIM) ? (i - (N_MID - OUT_DIM)) : -1;
            biasc[pos] = bias[i];
        }
        base += __popcll(m);
    }
    for (int idx = base + lane; idx < N_MID; idx += 64) {
        cmap[idx] = 0; ocol[idx] = -1; biasc[idx] = 0.f;
    }
    if (lane == 0) {
        const int Mc = base;
        int Mpad;
        if (Mc <= 768) Mpad = 768;
        else if (Mc <= 1024) Mpad = 1024;
        else Mpad = (Mc + 127) & ~127;     // v1 fallback territory
        hdr[0] = Mc; hdr[1] = Mpad; hdr[2] = 0;
        hdr[3] = Mpad / 32; hdr[4] = Mpad / 16;
    }
}

// ============================================================
// Setup B: gather eff_w -> bf16 MFMA B-fragment-major.
// ew2[((kstep*tpm + gt)*64 + lane)*8 + jj] = W[s][c]
//   s = kstep*32 + (lane>>4)*8 + jj, c = gt*16 + (lane&15)
// kstep<16: input rows; kstep>=16: compacted source s2=s-512, zero unless
// s2<c, both <Mc, different 32-chunk (same-chunk handled by tri).
// ============================================================
__global__ __launch_bounds__(NT)
void gather2_kernel(const float* __restrict__ w, const int* __restrict__ conn,
                    const int* __restrict__ hdr, const int* __restrict__ cmap,
                    unsigned short* __restrict__ ew2) {
    const int Mc = hdr[0], nch = hdr[3], tpm = hdr[4];
    if (tpm > 64) return;                      // v1 fallback case
    const int tid  = blockIdx.x * NT + threadIdx.x;
    const int lane = tid & 63;
    const int gl   = tid >> 6;
    const int gt   = gl % tpm;
    const int kstep = gl / tpm;
    if (kstep >= 16 + nch) return;
    const int c  = gt * 16 + (lane & 15);
    const int k0 = kstep * 32 + ((lane >> 4) << 3);
    unsigned short v[8];
#pragma unroll
    for (int jj = 0; jj < 8; ++jj) {
        const int s = k0 + jj;
        float val = 0.f;
        if (c < Mc) {
            const int cc = cmap[c];
            if (s < IN_DIM) {
                const size_t o = (size_t)s * N_MID + cc;
                val = w[o] * (float)conn[o];
            } else {
                const int s2 = s - IN_DIM;
                if (s2 < Mc && s2 < c && (s2 >> 5) != (c >> 5)) {
                    const size_t o = (size_t)(IN_DIM + cmap[s2]) * N_MID + cc;
                    val = w[o] * (float)conn[o];
                }
            }
        }
        v[jj] = f2bf(val);
    }
    *(uint4*)&ew2[((size_t)(kstep * tpm + gt) * 64 + lane) * 8] = *(uint4*)v;
}

// ============================================================
// Setup C: in-chunk triangle, fp32. tri[j][sl][cl] nonzero iff sl<cl && col<Mc.
// ============================================================
__global__ __launch_bounds__(NT)
void gather_tri_kernel(const float* __restrict__ w, const int* __restrict__ conn,
                       const int* __restrict__ hdr, const int* __restrict__ cmap,
                       float* __restrict__ tri) {
    const int Mc = hdr[0], nch = hdr[3];
    const int idx = blockIdx.x * NT + threadIdx.x;   // < 32*1024
    const int j  = idx >> 10;
    if (j >= nch) return;
    const int sl = (idx >> 5) & 31;
    const int cl = idx & 31;
    const int s = j * 32 + sl, c = j * 32 + cl;
    float v = 0.f;
    if (sl < cl && c < Mc) {
        const size_t o = (size_t)(IN_DIM + cmap[s]) * N_MID + cmap[c];
        v = w[o] * (float)conn[o];
    }
    tri[idx] = v;
}

// helper: static component select from float4 (constant-folded post-unroll)
__device__ __forceinline__ float f4c(const float4& v, int k) {
    return (k == 0) ? v.x : (k == 1) ? v.y : (k == 2) ? v.z : v.w;
}

// ============================================================
// Main kernel (net7): 256 blocks x 256 threads (4 waves), 64 rows/block.
// Mpad = TPW*64. One barrier per chunk. Chain-lean resolver.
// ============================================================
template <int TPW>
__global__ __launch_bounds__(256)
__attribute__((amdgpu_waves_per_eu(1, 1)))
void net7_kernel(const float* __restrict__ x,
                 const unsigned short* __restrict__ ew2,
                 const float* __restrict__ tri_g,
                 const int* __restrict__ hdr,
                 const int* __restrict__ ocol,
                 const float* __restrict__ biasc,
                 float* __restrict__ out) {
    if (hdr[1] != TPW * 64) return;
    const int Mc  = hdr[0];
    const int tpm = TPW * 4;                   // Mpad/16
    const int nch = TPW * 2;                   // Mpad/32

    __shared__ __align__(16) unsigned short xa[4096 * 8];      // 65,536 B
    __shared__ __align__(16) float stage2[32 * 68];            //  8,704 B ([col][row], stride 68)
    __shared__ __align__(16) unsigned short res2[2][2048];     //  8,192 B
    __shared__ __align__(16) float tri_lds[2][1024];           //  8,192 B
    __shared__ float bias_lds[1024];                           //  4,096 B
    __shared__ int   ocol_lds[1024];                           //  4,096 B
    // total ~98.8 KB -> 1 block/CU; 4 waves -> 1 wave/SIMD

    const int t = threadIdx.x, lane = t & 63, w = t >> 6;  // w in 0..3
    const int l15 = lane & 15, q = lane >> 4;
    const int r0 = blockIdx.x * 64;
    const int g0 = w * TPW;

    // ---- stage bias/ocol ----
    for (int i = t; i < TPW * 64; i += 256) {
        bias_lds[i] = biasc[i];
        ocol_lds[i] = ocol[i];
    }
    // ---- tri chunk 0 (wave 3) ----
    if (w == 3) {
        const float4* src = (const float4*)tri_g;
#pragma unroll
        for (int u = 0; u < 4; ++u)
            *(float4*)&tri_lds[0][(lane + 64 * u) * 4] = src[lane + 64 * u];
    }
    // ---- x -> bf16 A-fragment-contiguous: frag i = (kb*4+rr)*64 + lane2 ----
    for (int i = t; i < 4096; i += 256) {
        const int lane2 = i & 63, rrkb = i >> 6;
        const int rr = rrkb & 3, kb = rrkb >> 2;
        const int qq = lane2 >> 4, ll = lane2 & 15;
        const int row = rr * 16 + ll;
        const int k0 = kb * 32 + qq * 8;
        const float4 f0 = *(const float4*)&x[(size_t)(r0 + row) * IN_DIM + k0];
        const float4 f1 = *(const float4*)&x[(size_t)(r0 + row) * IN_DIM + k0 + 4];
        unsigned short vv[8] = {f2bf(f0.x), f2bf(f0.y), f2bf(f0.z), f2bf(f0.w),
                                f2bf(f1.x), f2bf(f1.y), f2bf(f1.z), f2bf(f1.w)};
        *(uint4*)&xa[(size_t)i * 8] = *(uint4*)vv;
    }
    __syncthreads();

    ffrag acc[TPW][4];
#pragma unroll
    for (int tt = 0; tt < TPW; ++tt)
#pragma unroll
        for (int rr = 0; rr < 4; ++rr) acc[tt][rr] = (ffrag)0.f;

    // ---- phase 1: input GEMM, 16 k-steps ----
#pragma unroll 1
    for (int kb = 0; kb < 16; ++kb) {
        bfrag a[4];
#pragma unroll
        for (int rr = 0; rr < 4; ++rr)
            a[rr] = *(const bfrag*)&xa[((kb * 4 + rr) * 64 + lane) * 8];
#pragma unroll
        for (int tt = 0; tt < TPW; ++tt) {
            if ((g0 + tt) * 16 < Mc) {
                const bfrag b = *(const bfrag*)&ew2[((size_t)(kb * tpm + g0 + tt) * 64 + lane) * 8];
#pragma unroll
                for (int rr = 0; rr < 4; ++rr)
                    acc[tt][rr] = __builtin_amdgcn_mfma_f32_16x16x32_bf16(a[rr], b, acc[tt][rr], 0, 0, 0);
            }
        }
    }

    // ---- phase 2: sequential chunks, ONE barrier each ----
#pragma unroll 1
    for (int j = 0; j < nch; ++j) {
        const int cbase = 32 * j;
        if (cbase >= Mc) break;                      // uniform

        if (j > 0) {                                 // apply res_{j-1}
            const int pr = (j - 1) & 1;
            bfrag a[4];
#pragma unroll
            for (int rr = 0; rr < 4; ++rr)
                a[rr] = *(const bfrag*)&res2[pr][(rr * 64 + lane) * 8];
#pragma unroll
            for (int tt = 0; tt < TPW; ++tt) {
                const int col0 = (g0 + tt) * 16;
                if (col0 >= cbase && col0 < Mc) {
                    const bfrag b = *(const bfrag*)&ew2[((size_t)((15 + j) * tpm + g0 + tt) * 64 + lane) * 8];
#pragma unroll
                    for (int rr = 0; rr < 4; ++rr)
                        acc[tt][rr] = __builtin_amdgcn_mfma_f32_16x16x32_bf16(a[rr], b, acc[tt][rr], 0, 0, 0);
                }
            }
        }

        const int ow = (2 * j) / TPW;                // owner wave (tiles 2j, 2j+1)
        if (w == ow) {
            // ---- stage own chunk tiles: [col][row] layout, b128 writes ----
#pragma unroll
            for (int tt = 0; tt < TPW; ++tt) {
                const int g = g0 + tt;
                if (g == 2 * j || g == 2 * j + 1) {
                    const int half = (g & 1) ? 16 : 0;
#pragma unroll
                    for (int rr = 0; rr < 4; ++rr)
                        *(ffrag*)&stage2[(half + l15) * 68 + rr * 16 + 4 * q] = acc[tt][rr];
                }
            }
            // ---- transposed resolve: lane = batch row ----
            const float* trij = tri_lds[j & 1];
            float reg[32];
#pragma unroll
            for (int c = 0; c < 32; ++c) reg[c] = stage2[c * 68 + lane];

            float4 tr[2][8];                         // tri row double-buffer
#pragma unroll
            for (int u = 0; u < 8; ++u) tr[0][u] = *(const float4*)&trij[u * 4];

#pragma unroll
            for (int c = 0; c < 32; ++c) {
                const int cb = c & 1;
                if (c < 31) {
#pragma unroll
                    for (int u = 0; u < 8; ++u)
                        tr[cb ^ 1][u] = *(const float4*)&trij[(c + 1) * 32 + u * 4];
                }
                const float s  = __fdividef(1.f, 1.f + __expf(-reg[c]));
                const float rs = s + bias_lds[cbase + c];
                reg[c] = rs;
#pragma unroll
                for (int k = c + 1; k < 32; ++k)
                    reg[k] = fmaf(rs, f4c(tr[cb][k >> 2], k & 3), reg[k]);
            }
            // ---- bulk res2 write: 4 x ds_write_b128 (A-frag layout, bf16) ----
            {
                unsigned short* resb = res2[j & 1];
                const int rowA = ((lane >> 4) * 64 + (lane & 15)) * 8;
#pragma unroll
                for (int qA = 0; qA < 4; ++qA) {
                    unsigned int u[4];
#pragma unroll
                    for (int i = 0; i < 4; ++i)
                        u[i] = (unsigned int)f2bf(reg[qA * 8 + 2 * i]) |
                               ((unsigned int)f2bf(reg[qA * 8 + 2 * i + 1]) << 16);
                    *(uint4*)&resb[rowA + qA * 128] = *(uint4*)u;
                }
            }
            // ---- bulk out stores ----
#pragma unroll
            for (int c = 0; c < 32; ++c) {
                const int oc = ocol_lds[cbase + c];  // uniform
                if (oc >= 0)
                    out[(size_t)(r0 + lane) * OUT_DIM + oc] = reg[c];
            }
        } else if (w == ((ow + 2) & 3)) {
            // prefetch tri for chunk j+1 (overlaps resolve)
            const int jn = j + 1;
            if (jn < nch && 32 * jn < Mc) {
                const float4* src = (const float4*)(tri_g + (size_t)jn * 1024);
#pragma unroll
                for (int u = 0; u < 4; ++u)
                    *(float4*)&tri_lds[jn & 1][(lane + 64 * u) * 4] = src[lane + 64 * u];
            }
        }
        __syncthreads();                             // the ONE barrier
    }
}

// ============================================================
// Fallback (Mc > 1024 or tiny ws): round-1 monolithic fp32 kernel.
// ============================================================
__global__ __launch_bounds__(NT, 4)
void net_v1_kernel(const float* __restrict__ x,
                   const float* __restrict__ wsrc,
                   const int* __restrict__ conn,
                   const float* __restrict__ bias,
                   const int* __restrict__ exist,
                   const int* __restrict__ hdr,   // null = always run
                   float* __restrict__ out) {
    if (hdr && hdr[1] <= 1024) return;
    __shared__ float xs[16 * XPAD];
    __shared__ float res_s[2][16];
    float* bias_s  = xs;
    float* exist_s = xs + N_MID;
    const int t = threadIdx.x, rg = t & 3, cg = t >> 2;
    const int r0 = blockIdx.x * 16;
    const int c0 = cg * 20;
    {
        const float4* xg = (const float4*)(x + (size_t)r0 * IN_DIM);
        for (int idx = t; idx < 16 * IN_DIM / 4; idx += NT) {
            const int r = idx >> 7, jj = idx & 127;
            *(float4*)&xs[r * XPAD + jj * 4] = xg[idx];
        }
    }
    __syncthreads();
    float acc[4][20];
#pragma unroll
    for (int a = 0; a < 4; ++a)
#pragma unroll
        for (int k = 0; k < 20; ++k) acc[a][k] = 0.f;
    for (int j = 0; j < IN_DIM; ++j) {
        const size_t woff = (size_t)j * N_MID + c0;
        const float xv0 = xs[rg * XPAD + j];
        const float xv1 = xs[(rg + 4) * XPAD + j];
        const float xv2 = xs[(rg + 8) * XPAD + j];
        const float xv3 = xs[(rg + 12) * XPAD + j];
#pragma unroll
        for (int qq = 0; qq < 5; ++qq) {
            float4 w4 = *(const float4*)(wsrc + woff + qq * 4);
            const int4 c4 = *(const int4*)(conn + woff + qq * 4);
            w4.x *= (float)c4.x; w4.y *= (float)c4.y;
            w4.z *= (float)c4.z; w4.w *= (float)c4.w;
            const float wq[4] = {w4.x, w4.y, w4.z, w4.w};
#pragma unroll
            for (int u = 0; u < 4; ++u) {
                const int k = qq * 4 + u;
                acc[0][k] = fmaf(xv0, wq[u], acc[0][k]);
                acc[1][k] = fmaf(xv1, wq[u], acc[1][k]);
                acc[2][k] = fmaf(xv2, wq[u], acc[2][k]);
                acc[3][k] = fmaf(xv3, wq[u], acc[3][k]);
            }
        }
    }
    __syncthreads();
    for (int idx = t; idx < N_MID; idx += NT) {
        bias_s[idx]  = bias[idx];
        exist_s[idx] = (float)exist[idx];
    }
    __syncthreads();
    int p = 0;
    for (int bb = 0; bb < 64; ++bb) {
#pragma unroll
        for (int kk = 0; kk < 20; ++kk) {
            const int i = bb * 20 + kk;
            const float e = exist_s[i];
            if (e != 0.f) {
                if (cg == bb) {
                    const float bv = bias_s[i];
#pragma unroll
                    for (int a = 0; a < 4; ++a) {
                        const float v = acc[a][kk];
                        const float s = __fdividef(1.f, 1.f + __expf(-v));
                        const float res = (s + bv) * e;
                        res_s[p][rg + 4 * a] = res;
                        if (i >= N_MID - OUT_DIM)
                            out[(size_t)(r0 + rg + 4 * a) * OUT_DIM + (i - (N_MID - OUT_DIM))] = res;
                    }
                }
                __syncthreads();
                const float rv0 = res_s[p][rg];
                const float rv1 = res_s[p][rg + 4];
                const float rv2 = res_s[p][rg + 8];
                const float rv3 = res_s[p][rg + 12];
                const size_t woff = (size_t)(IN_DIM + i) * N_MID + c0;
                if (cg > bb) {
#pragma unroll
                    for (int qq = 0; qq < 5; ++qq) {
                        float4 w4 = *(const float4*)(wsrc + woff + qq * 4);
                        const int4 c4 = *(const int4*)(conn + woff + qq * 4);
                        w4.x *= (float)c4.x; w4.y *= (float)c4.y;
                        w4.z *= (float)c4.z; w4.w *= (float)c4.w;
                        const float wq[4] = {w4.x, w4.y, w4.z, w4.w};
#pragma unroll
                        for (int u = 0; u < 4; ++u) {
                            const int k = qq * 4 + u;
                            acc[0][k] = fmaf(rv0, wq[u], acc[0][k]);
                            acc[1][k] = fmaf(rv1, wq[u], acc[1][k]);
                            acc[2][k] = fmaf(rv2, wq[u], acc[2][k]);
                            acc[3][k] = fmaf(rv3, wq[u], acc[3][k]);
                        }
                    }
                } else if (cg == bb) {
#pragma unroll
                    for (int k = kk + 1; k < 20; ++k) {
                        float ww = wsrc[woff + k] * (float)conn[woff + k];
                        acc[0][k] = fmaf(rv0, ww, acc[0][k]);
                        acc[1][k] = fmaf(rv1, ww, acc[1][k]);
                        acc[2][k] = fmaf(rv2, ww, acc[2][k]);
                        acc[3][k] = fmaf(rv3, ww, acc[3][k]);
                    }
                }
                p ^= 1;
            }
        }
    }
}

extern "C" void kernel_launch(void* const* d_in, const int* in_sizes, int n_in,
                              void* d_out, int out_size, void* d_ws, size_t ws_size,
                              hipStream_t stream) {
    const float* x      = (const float*)d_in[0];
    const float* weight = (const float*)d_in[1];
    const float* bias   = (const float*)d_in[2];
    const int*   conn   = (const int*)d_in[3];
    const int*   exist  = (const int*)d_in[4];
    float*       out    = (float*)d_out;

    if (ws_size >= WS_NEED) {
        char* ws = (char*)d_ws;
        unsigned short* ew2  = (unsigned short*)ws;
        float*          tri  = (float*)(ws + TRI_OFF);
        int*            hdr  = (int*)(ws + HDR_OFF);
        int*            cmap = (int*)(ws + CMAP_OFF);
        int*            ocolp= (int*)(ws + OCOL_OFF);
        float*          bsc  = (float*)(ws + BIASC_OFF);

        build_maps_kernel<<<1, 64, 0, stream>>>(exist, bias, hdr, cmap, ocolp, bsc);
        gather2_kernel<<<768, NT, 0, stream>>>(weight, conn, hdr, cmap, ew2);
        gather_tri_kernel<<<128, NT, 0, stream>>>(weight, conn, hdr, cmap, tri);
        net7_kernel<12><<<256, 256, 0, stream>>>(x, ew2, tri, hdr, ocolp, bsc, out);
        net7_kernel<16><<<256, 256, 0, stream>>>(x, ew2, tri, hdr, ocolp, bsc, out);
        net_v1_kernel<<<BATCH / 16, NT, 0, stream>>>(x, weight, conn, bias, exist, hdr, out);
    } else {
        net_v1_kernel<<<BATCH / 16, NT, 0, stream>>>(x, weight, conn, bias, exist, nullptr, out);
    }
}